// Round 1
// baseline (443.036 us; speedup 1.0000x reference)
//
#include <hip/hip_runtime.h>
#include <math.h>

// GraphAttn: B=16, N=2048, feat = C*F = 64.
//  xf = W @ x + bias   (per batch, 2048x2048 * 2048x64)
//  s1[b,o] = xf[b,o,:] . att1
//  s2[b,o] = nf[b,o,:] . att2  ==  W @ (n . att2) + bias*sum(att2)   [linearity]
//  a[b,i,j] = leaky_relu(s1[j] + s2[i]);  softmax over i (columns j normalized)
//  out[b,i,:] = sum_j softmax(a)[i,j] * xf[b,j,:]
//
// ws layout (floats): xf[B*N*64] | s1[B*N] | s2[B*N] | mcol[B*N] | zinv[B*N] | nt[N*B]
// total = 9,043,968 bytes

#define BB 16
#define NN 2048
#define FEAT 64
#define BM 64
#define BK 32

__device__ __forceinline__ float lrelu(float t) {
    return fmaxf(t, 0.2f * t);   // slope 1 for t>0, 0.2 for t<0; monotone
}

// ntilde[i*B+b] = sum_hw n[b,i,hw]*att2[hw]
__global__ __launch_bounds__(256) void k0_ntilde(
        const float* __restrict__ n, const float* __restrict__ att2,
        float* __restrict__ nt) {
    int t = blockIdx.x * 256 + threadIdx.x;   // t = b*N + i
    int b = t >> 11, i = t & (NN - 1);
    const float4* row = (const float4*)(n + ((size_t)b * NN + i) * FEAT);
    const float4* a2  = (const float4*)att2;
    float s = 0.f;
#pragma unroll
    for (int q = 0; q < 16; ++q) {
        float4 v = row[q], w = a2[q];
        s += v.x * w.x + v.y * w.y + v.z * w.z + v.w * w.w;
    }
    nt[i * BB + b] = s;
}

// xf[b] = W @ x[b] + bias  -- fp32 tiled GEMM, 64x64 tile, BK=32
__global__ __launch_bounds__(256) void k1_conv(
        const float* __restrict__ x, const float* __restrict__ W,
        const float* __restrict__ bias, float* __restrict__ xf) {
    __shared__ float Ws[BK][BM + 4];   // [k][m], stride 68 floats (16B aligned rows)
    __shared__ float Xs[BK][FEAT];     // [k][hw]
    const int o0 = blockIdx.x * BM;
    const int b  = blockIdx.y;
    const int t  = threadIdx.x;
    const int ty = t >> 4, tx = t & 15;
    float acc[4][4] = {};
    for (int k0 = 0; k0 < NN; k0 += BK) {
#pragma unroll
        for (int r = 0; r < 2; ++r) {            // W tile 64x32
            int v = t + r * 256;
            int m = v >> 3, k = (v & 7) * 4;
            float4 w4 = *(const float4*)(W + (size_t)(o0 + m) * NN + k0 + k);
            Ws[k + 0][m] = w4.x; Ws[k + 1][m] = w4.y;
            Ws[k + 2][m] = w4.z; Ws[k + 3][m] = w4.w;
        }
#pragma unroll
        for (int r = 0; r < 2; ++r) {            // X tile 32x64
            int v = t + r * 256;
            int k = v >> 4, hw = (v & 15) * 4;
            *(float4*)&Xs[k][hw] =
                *(const float4*)(x + ((size_t)b * NN + k0 + k) * FEAT + hw);
        }
        __syncthreads();
#pragma unroll
        for (int kk = 0; kk < BK; ++kk) {
            float a[4], c[4];
            *(float4*)a = *(const float4*)&Ws[kk][ty * 4];
            *(float4*)c = *(const float4*)&Xs[kk][tx * 4];
#pragma unroll
            for (int ii = 0; ii < 4; ++ii)
#pragma unroll
                for (int ff = 0; ff < 4; ++ff)
                    acc[ii][ff] += a[ii] * c[ff];
        }
        __syncthreads();
    }
#pragma unroll
    for (int ii = 0; ii < 4; ++ii) {
        int o = o0 + ty * 4 + ii;
        float bv = bias[o];
        float4 r = make_float4(acc[ii][0] + bv, acc[ii][1] + bv,
                               acc[ii][2] + bv, acc[ii][3] + bv);
        *(float4*)(xf + ((size_t)b * NN + o) * FEAT + tx * 4) = r;
    }
}

// s2[b,o] = sum_i W[o,i]*nt[i,b] + bias[o]*sum(att2)
__global__ __launch_bounds__(256) void k2_s2(
        const float* __restrict__ W, const float* __restrict__ nt,
        const float* __restrict__ bias, const float* __restrict__ att2,
        float* __restrict__ s2) {
    int t = blockIdx.x * 256 + threadIdx.x;   // t = o*16 + b
    int o = t >> 4, b = t & 15;
    float acc = 0.f;
    for (int i = 0; i < NN; i += 4) {
        float4 w4 = *(const float4*)(W + (size_t)o * NN + i);
        acc += w4.x * nt[(i + 0) * BB + b] + w4.y * nt[(i + 1) * BB + b]
             + w4.z * nt[(i + 2) * BB + b] + w4.w * nt[(i + 3) * BB + b];
    }
    float A2 = 0.f;
#pragma unroll
    for (int q = 0; q < FEAT; ++q) A2 += att2[q];
    s2[(size_t)b * NN + o] = acc + bias[o] * A2;
}

// s1[b,o] = xf[b,o,:] . att1
__global__ __launch_bounds__(256) void k2b_s1(
        const float* __restrict__ xf, const float* __restrict__ att1,
        float* __restrict__ s1) {
    int t = blockIdx.x * 256 + threadIdx.x;   // t = b*N + o
    const float4* row = (const float4*)(xf + (size_t)t * FEAT);
    const float4* a1  = (const float4*)att1;
    float s = 0.f;
#pragma unroll
    for (int q = 0; q < 16; ++q) {
        float4 v = row[q], w = a1[q];
        s += v.x * w.x + v.y * w.y + v.z * w.z + v.w * w.w;
    }
    s1[t] = s;
}

// per column j: m_j = lr(s1_j + max_i s2_i); zinv_j = 1/sum_i exp(lr(s1_j+s2_i)-m_j)
__global__ __launch_bounds__(256) void k3_stats(
        const float* __restrict__ s1, const float* __restrict__ s2,
        float* __restrict__ mcol, float* __restrict__ zinv) {
    __shared__ float s2sh[NN];
    __shared__ float red[256];
    const int b = blockIdx.y, j0 = blockIdx.x * 256, t = threadIdx.x;
    float mx = -INFINITY;
#pragma unroll
    for (int r = 0; r < NN / 256; ++r) {
        float v = s2[(size_t)b * NN + r * 256 + t];
        s2sh[r * 256 + t] = v;
        mx = fmaxf(mx, v);
    }
    red[t] = mx;
    __syncthreads();
    for (int s = 128; s > 0; s >>= 1) {
        if (t < s) red[t] = fmaxf(red[t], red[t + s]);
        __syncthreads();
    }
    const float s2max = red[0];
    const int j = j0 + t;
    const float sj = s1[(size_t)b * NN + j];
    const float m = lrelu(sj + s2max);   // lr monotone -> this IS max_i
    float z = 0.f;
    for (int i = 0; i < NN; ++i)
        z += __expf(lrelu(sj + s2sh[i]) - m);
    mcol[(size_t)b * NN + j] = m;
    zinv[(size_t)b * NN + j] = 1.0f / z;
}

// out[b,i,:] = sum_j exp(lr(s1j+s2i)-m_j)*zinv_j * xf[b,j,:]
__global__ __launch_bounds__(256) void k4_out(
        const float* __restrict__ xf, const float* __restrict__ s1,
        const float* __restrict__ s2, const float* __restrict__ mcol,
        const float* __restrict__ zinv, float* __restrict__ out) {
    __shared__ float Xs[BK][FEAT];      // xf j-tile
    __shared__ float Cs[BK][BM + 4];    // coefficients [kk][i_local]
    const int i0 = blockIdx.x * BM;
    const int b  = blockIdx.y;
    const int t  = threadIdx.x;
    const int ty = t >> 4, tx = t & 15;
    const int il = t & 63, kg = t >> 6;           // for Cs generation
    const float si = s2[(size_t)b * NN + i0 + il]; // reused across all j-tiles
    float acc[4][4] = {};
    for (int j0 = 0; j0 < NN; j0 += BK) {
#pragma unroll
        for (int r = 0; r < 2; ++r) {
            int v = t + r * 256;
            int k = v >> 4, hw = (v & 15) * 4;
            *(float4*)&Xs[k][hw] =
                *(const float4*)(xf + ((size_t)b * NN + j0 + k) * FEAT + hw);
        }
#pragma unroll
        for (int r = 0; r < 8; ++r) {             // 32x64 coefficients
            int kk = kg + r * 4;
            int j  = j0 + kk;
            float sj = s1[(size_t)b * NN + j];
            float c  = __expf(lrelu(sj + si) - mcol[(size_t)b * NN + j])
                     * zinv[(size_t)b * NN + j];
            Cs[kk][il] = c;
        }
        __syncthreads();
#pragma unroll
        for (int kk = 0; kk < BK; ++kk) {
            float a[4], c[4];
            *(float4*)a = *(const float4*)&Cs[kk][ty * 4];
            *(float4*)c = *(const float4*)&Xs[kk][tx * 4];
#pragma unroll
            for (int ii = 0; ii < 4; ++ii)
#pragma unroll
                for (int ff = 0; ff < 4; ++ff)
                    acc[ii][ff] += a[ii] * c[ff];
        }
        __syncthreads();
    }
#pragma unroll
    for (int ii = 0; ii < 4; ++ii) {
        *(float4*)(out + ((size_t)b * NN + i0 + ty * 4 + ii) * FEAT + tx * 4) =
            make_float4(acc[ii][0], acc[ii][1], acc[ii][2], acc[ii][3]);
    }
}

extern "C" void kernel_launch(void* const* d_in, const int* in_sizes, int n_in,
                              void* d_out, int out_size, void* d_ws, size_t ws_size,
                              hipStream_t stream) {
    const float* x      = (const float*)d_in[0];   // (16,2048,4,16)
    const float* n      = (const float*)d_in[1];   // (16,2048,4,16)
    const float* conv_w = (const float*)d_in[2];   // (2048,2048,1,1)
    const float* conv_b = (const float*)d_in[3];   // (2048,)
    const float* att1   = (const float*)d_in[4];   // (1,64)
    const float* att2   = (const float*)d_in[5];   // (1,64)
    float* outp = (float*)d_out;

    float* ws   = (float*)d_ws;
    float* xf   = ws;                              // B*N*64
    float* s1   = xf + (size_t)BB * NN * FEAT;     // B*N
    float* s2   = s1 + (size_t)BB * NN;
    float* mcol = s2 + (size_t)BB * NN;
    float* zinv = mcol + (size_t)BB * NN;
    float* nt   = zinv + (size_t)BB * NN;          // N*B

    k0_ntilde<<<dim3(BB * NN / 256), dim3(256), 0, stream>>>(n, att2, nt);
    k1_conv<<<dim3(NN / BM, BB), dim3(256), 0, stream>>>(x, conv_w, conv_b, xf);
    k2_s2<<<dim3(NN * BB / 256), dim3(256), 0, stream>>>(conv_w, nt, conv_b, att2, s2);
    k2b_s1<<<dim3(BB * NN / 256), dim3(256), 0, stream>>>(xf, att1, s1);
    k3_stats<<<dim3(NN / 256, BB), dim3(256), 0, stream>>>(s1, s2, mcol, zinv);
    k4_out<<<dim3(NN / BM, BB), dim3(256), 0, stream>>>(xf, s1, s2, mcol, zinv, outp);
}

// Round 3
// 332.380 us; speedup vs baseline: 1.3329x; 1.3329x over previous
//
#include <hip/hip_runtime.h>
#include <math.h>

// GraphAttn: B=16, N=2048, feat = C*F = 64.
//  xf = W @ x + bias   (per batch, 2048x2048 * 2048x64)
//  s1[b,o] = xf[b,o,:] . att1
//  s2[b,o] = W @ (n . att2) + bias*sum(att2)   [conv linearity]
//  a[b,i,j] = leaky_relu(s1[j] + s2[i]);  softmax over i (columns j normalized)
//  out[b,i,:] = sum_j softmax(a)[i,j] * xf[b,j,:]
//
// Separable softmax: exp(lr(s1_j+s2_i)) factors into e^{s1_j}e^{s2_i} (arg>=0)
// or e^{.2 s1_j}e^{.2 s2_i} (arg<0). Sorting s1/s2 per batch turns the i- and
// j-sums into prefix/suffix sums + binary search: O(N^2 F) -> O(N F log N).
//
// xf lives in d_out (k4_sep never reads xf and overwrites all of d_out).
// ws floats: PA[B*N*64] PB[B*N*64] + 10 * B*N small arrays + CTA/CTB  ~= 17.4 MB

#define BB 16
#define NN 2048
#define FEAT 64
#define BM 64
#define BK 32
#define NCH 16      // scan chunks per batch
#define CHL 128     // chunk length (NCH*CHL == NN)

__device__ __forceinline__ float lrelu(float t) {
    return fmaxf(t, 0.2f * t);
}

// ---------------------------------------------------------------- k0: ntilde
// nt[i*B+b] = sum_hw n[b,i,hw]*att2[hw]
__global__ __launch_bounds__(256) void k0_ntilde(
        const float* __restrict__ n, const float* __restrict__ att2,
        float* __restrict__ nt) {
    int t = blockIdx.x * 256 + threadIdx.x;   // t = b*N + i
    int b = t >> 11, i = t & (NN - 1);
    const float4* row = (const float4*)(n + ((size_t)b * NN + i) * FEAT);
    const float4* a2  = (const float4*)att2;
    float s = 0.f;
#pragma unroll
    for (int q = 0; q < 16; ++q) {
        float4 v = row[q], w = a2[q];
        s += v.x * w.x + v.y * w.y + v.z * w.z + v.w * w.w;
    }
    nt[i * BB + b] = s;
}

// ---------------------------------------------------------------- k1: conv
// xf[b] = W @ x[b] + bias  -- fp32 tiled GEMM, 64x64 tile, BK=32
__global__ __launch_bounds__(256) void k1_conv(
        const float* __restrict__ x, const float* __restrict__ W,
        const float* __restrict__ bias, float* __restrict__ xf) {
    __shared__ float Ws[BK][BM + 4];
    __shared__ float Xs[BK][FEAT];
    const int o0 = blockIdx.x * BM;
    const int b  = blockIdx.y;
    const int t  = threadIdx.x;
    const int ty = t >> 4, tx = t & 15;
    float acc[4][4] = {};
    for (int k0 = 0; k0 < NN; k0 += BK) {
#pragma unroll
        for (int r = 0; r < 2; ++r) {            // W tile 64x32
            int v = t + r * 256;
            int m = v >> 3, k = (v & 7) * 4;
            float4 w4 = *(const float4*)(W + (size_t)(o0 + m) * NN + k0 + k);
            Ws[k + 0][m] = w4.x; Ws[k + 1][m] = w4.y;
            Ws[k + 2][m] = w4.z; Ws[k + 3][m] = w4.w;
        }
#pragma unroll
        for (int r = 0; r < 2; ++r) {            // X tile 32x64
            int v = t + r * 256;
            int k = v >> 4, hw = (v & 15) * 4;
            *(float4*)&Xs[k][hw] =
                *(const float4*)(x + ((size_t)b * NN + k0 + k) * FEAT + hw);
        }
        __syncthreads();
#pragma unroll
        for (int kk = 0; kk < BK; ++kk) {
            float a[4], c[4];
            *(float4*)a = *(const float4*)&Ws[kk][ty * 4];
            *(float4*)c = *(const float4*)&Xs[kk][tx * 4];
#pragma unroll
            for (int ii = 0; ii < 4; ++ii)
#pragma unroll
                for (int ff = 0; ff < 4; ++ff)
                    acc[ii][ff] += a[ii] * c[ff];
        }
        __syncthreads();
    }
#pragma unroll
    for (int ii = 0; ii < 4; ++ii) {
        int o = o0 + ty * 4 + ii;
        float bv = bias[o];
        float4 r = make_float4(acc[ii][0] + bv, acc[ii][1] + bv,
                               acc[ii][2] + bv, acc[ii][3] + bv);
        *(float4*)(xf + ((size_t)b * NN + o) * FEAT + tx * 4) = r;
    }
}

// ---------------------------------------------------------------- k2: s2
__global__ __launch_bounds__(256) void k2_s2(
        const float* __restrict__ W, const float* __restrict__ nt,
        const float* __restrict__ bias, const float* __restrict__ att2,
        float* __restrict__ s2) {
    int t = blockIdx.x * 256 + threadIdx.x;   // t = o*16 + b
    int o = t >> 4, b = t & 15;
    float acc = 0.f;
    for (int i = 0; i < NN; i += 4) {
        float4 w4 = *(const float4*)(W + (size_t)o * NN + i);
        acc += w4.x * nt[(i + 0) * BB + b] + w4.y * nt[(i + 1) * BB + b]
             + w4.z * nt[(i + 2) * BB + b] + w4.w * nt[(i + 3) * BB + b];
    }
    float A2 = 0.f;
#pragma unroll
    for (int q = 0; q < FEAT; ++q) A2 += att2[q];
    s2[(size_t)b * NN + o] = acc + bias[o] * A2;
}

// ---------------------------------------------------------------- k2b: s1
__global__ __launch_bounds__(256) void k2b_s1(
        const float* __restrict__ xf, const float* __restrict__ att1,
        float* __restrict__ s1) {
    int t = blockIdx.x * 256 + threadIdx.x;   // t = b*N + o
    const float4* row = (const float4*)(xf + (size_t)t * FEAT);
    const float4* a1  = (const float4*)att1;
    float s = 0.f;
#pragma unroll
    for (int q = 0; q < 16; ++q) {
        float4 v = row[q], w = a1[q];
        s += v.x * w.x + v.y * w.y + v.z * w.z + v.w * w.w;
    }
    s1[t] = s;
}

// ---------------------------------------------------------------- sort+scan
__device__ __forceinline__ void scan2048(float* buf, int t) {
    // inclusive Hillis-Steele over 2048 elems with 1024 threads
    for (int off = 1; off < 2048; off <<= 1) {
        int i0 = t, i1 = t + 1024;
        float x0 = (i0 >= off) ? buf[i0 - off] : 0.f;
        float c0 = buf[i0];
        float x1 = (i1 >= off) ? buf[i1 - off] : 0.f;
        float c1 = buf[i1];
        __syncthreads();
        buf[i0] = c0 + x0;
        buf[i1] = c1 + x1;
        __syncthreads();
    }
}

// blockIdx.x: 0 -> sort s1 (keys+perm); 1 -> sort s2 (+ exp prefix/suffix sums)
__global__ __launch_bounds__(1024) void ksort(
        const float* __restrict__ s1, const float* __restrict__ s2,
        float* __restrict__ s1s, int* __restrict__ p1,
        float* __restrict__ s2s, float* __restrict__ E1suf,
        float* __restrict__ E2) {
    __shared__ float key[2048];
    __shared__ int   val[2048];
    __shared__ float buf[2048];
    const int b = blockIdx.y, arr = blockIdx.x, t = threadIdx.x;
    const float* src = (arr == 0 ? s1 : s2) + (size_t)b * NN;
    key[t] = src[t]; key[t + 1024] = src[t + 1024];
    val[t] = t;      val[t + 1024] = t + 1024;
    __syncthreads();
    for (int k = 2; k <= 2048; k <<= 1) {
        for (int j = k >> 1; j > 0; j >>= 1) {
#pragma unroll
            for (int r = 0; r < 2; ++r) {
                int i = r * 1024 + t;
                int l = i ^ j;
                if (l > i) {
                    bool up = ((i & k) == 0);
                    float ki = key[i], kl = key[l];
                    if (up ? (ki > kl) : (ki < kl)) {
                        key[i] = kl; key[l] = ki;
                        int vi = val[i]; val[i] = val[l]; val[l] = vi;
                    }
                }
            }
            __syncthreads();
        }
    }
    const size_t base = (size_t)b * NN;
    if (arr == 0) {
        s1s[base + t] = key[t]; s1s[base + t + 1024] = key[t + 1024];
        p1[base + t]  = val[t]; p1[base + t + 1024]  = val[t + 1024];
    } else {
        s2s[base + t] = key[t]; s2s[base + t + 1024] = key[t + 1024];
        // E2 = inclusive prefix of e^{0.2*s2s}
        buf[t] = __expf(0.2f * key[t]);
        buf[t + 1024] = __expf(0.2f * key[t + 1024]);
        __syncthreads();
        scan2048(buf, t);
        E2[base + t] = buf[t]; E2[base + t + 1024] = buf[t + 1024];
        __syncthreads();
        // E1suf = inclusive suffix of e^{s2s} (scan of reversed array)
        buf[t] = __expf(key[2047 - t]);
        buf[t + 1024] = __expf(key[2047 - (t + 1024)]);
        __syncthreads();
        scan2048(buf, t);
        E1suf[base + 2047 - t] = buf[t];
        E1suf[base + 2047 - (t + 1024)] = buf[t + 1024];
    }
}

// ---------------------------------------------------------------- k_ab
// per sorted position t: z = e^{s1}*sum_{s2>=-s1} e^{s2} + e^{.2 s1}*sum_{s2<-s1} e^{.2 s2}
// as[t] = e^{s1}/z ; bs[t] = e^{.2 s1}/z     (sorted-s1 order)
__global__ __launch_bounds__(256) void k_ab(
        const float* __restrict__ s1s, const float* __restrict__ s2s,
        const float* __restrict__ E1suf, const float* __restrict__ E2,
        float* __restrict__ as, float* __restrict__ bs) {
    int idx = blockIdx.x * 256 + threadIdx.x;   // b*N + t
    int b = idx >> 11;
    const size_t base = (size_t)b * NN;
    float s1v = s1s[idx];
    float thr = -s1v;
    const float* S2 = s2s + base;
    int lo = 0, hi = NN;
    while (lo < hi) { int mid = (lo + hi) >> 1; if (S2[mid] < thr) lo = mid + 1; else hi = mid; }
    float e1 = (lo < NN) ? E1suf[base + lo] : 0.f;       // sum over s2 >= thr
    float e2 = (lo > 0)  ? E2[base + lo - 1] : 0.f;      // sum over s2 <  thr
    float ea = __expf(s1v), eb = __expf(0.2f * s1v);
    float zi = 1.0f / (ea * e1 + eb * e2);
    as[idx] = ea * zi;
    bs[idx] = eb * zi;
}

// ---------------------------------------------------------------- scans of a*xf, b*xf
// pass A: per (b, chunk): chunk totals over 128 sorted rows, lane = feature
__global__ __launch_bounds__(64) void kscanA(
        const int* __restrict__ p1, const float* __restrict__ as,
        const float* __restrict__ bs, const float* __restrict__ xf,
        float* __restrict__ CTA, float* __restrict__ CTB) {
    const int b = blockIdx.y, c = blockIdx.x, f = threadIdx.x;
    const size_t base = (size_t)b * NN;
    float sA = 0.f, sB = 0.f;
#pragma unroll 8
    for (int r = 0; r < CHL; ++r) {
        int t = c * CHL + r;
        int j = p1[base + t];
        float xv = xf[(base + j) * FEAT + f];
        sA += as[base + t] * xv;
        sB += bs[base + t] * xv;
    }
    CTA[((size_t)b * NCH + c) * FEAT + f] = sA;
    CTB[((size_t)b * NCH + c) * FEAT + f] = sB;
}

// pass B: PA[t][f] = inclusive SUFFIX sum of as*xf ; PB[t][f] = inclusive PREFIX of bs*xf
__global__ __launch_bounds__(64) void kscanB(
        const int* __restrict__ p1, const float* __restrict__ as,
        const float* __restrict__ bs, const float* __restrict__ xf,
        const float* __restrict__ CTA, const float* __restrict__ CTB,
        float* __restrict__ PA, float* __restrict__ PB) {
    const int b = blockIdx.y, c = blockIdx.x, f = threadIdx.x;
    const size_t base = (size_t)b * NN;
    float offA = 0.f, offB = 0.f;
    for (int cc = 0; cc < NCH; ++cc) {
        float av = CTA[((size_t)b * NCH + cc) * FEAT + f];
        float bv = CTB[((size_t)b * NCH + cc) * FEAT + f];
        if (cc > c) offA += av;
        if (cc < c) offB += bv;
    }
    float run = offB;
#pragma unroll 4
    for (int r = 0; r < CHL; ++r) {
        int t = c * CHL + r;
        int j = p1[base + t];
        float xv = xf[(base + j) * FEAT + f];
        run += bs[base + t] * xv;
        PB[(base + t) * FEAT + f] = run;
    }
    run = offA;
#pragma unroll 4
    for (int r = CHL - 1; r >= 0; --r) {
        int t = c * CHL + r;
        int j = p1[base + t];
        float xv = xf[(base + j) * FEAT + f];
        run += as[base + t] * xv;
        PA[(base + t) * FEAT + f] = run;
    }
}

// ---------------------------------------------------------------- k4: output
// out[i,f] = e^{s2_i} * PA[t_i][f] + e^{.2 s2_i} * PB[t_i-1][f],
// t_i = #{ sorted s1 < -s2_i } (binary search)
// Reads only PA/PB/s2/s1s; overwrites ALL of d_out (so xf may alias d_out).
__global__ __launch_bounds__(256) void k4_sep(
        const float* __restrict__ s2, const float* __restrict__ s1s,
        const float* __restrict__ PA, const float* __restrict__ PB,
        float* __restrict__ out) {
    const int b = blockIdx.y;
    const int i = blockIdx.x * 16 + (threadIdx.x >> 4);
    const int fg = threadIdx.x & 15;
    const size_t base = (size_t)b * NN;
    float s2v = s2[base + i];
    float thr = -s2v;
    const float* S1 = s1s + base;
    int lo = 0, hi = NN;
    while (lo < hi) { int mid = (lo + hi) >> 1; if (S1[mid] < thr) lo = mid + 1; else hi = mid; }
    float eA = __expf(s2v), eB = __expf(0.2f * s2v);
    float4 pa = make_float4(0.f, 0.f, 0.f, 0.f);
    float4 pb = make_float4(0.f, 0.f, 0.f, 0.f);
    if (lo < NN) pa = *(const float4*)(PA + (base + lo) * FEAT + fg * 4);
    if (lo > 0)  pb = *(const float4*)(PB + (base + lo - 1) * FEAT + fg * 4);
    float4 o;
    o.x = eA * pa.x + eB * pb.x;
    o.y = eA * pa.y + eB * pb.y;
    o.z = eA * pa.z + eB * pb.z;
    o.w = eA * pa.w + eB * pb.w;
    *(float4*)(out + (base + i) * FEAT + fg * 4) = o;
}

extern "C" void kernel_launch(void* const* d_in, const int* in_sizes, int n_in,
                              void* d_out, int out_size, void* d_ws, size_t ws_size,
                              hipStream_t stream) {
    const float* x      = (const float*)d_in[0];
    const float* n      = (const float*)d_in[1];
    const float* conv_w = (const float*)d_in[2];
    const float* conv_b = (const float*)d_in[3];
    const float* att1   = (const float*)d_in[4];
    const float* att2   = (const float*)d_in[5];
    float* outp = (float*)d_out;

    // xf aliases d_out: k4_sep never reads xf and fully overwrites d_out.
    float* xf = outp;

    float* ws    = (float*)d_ws;
    float* PA    = ws;                               // B*N*64
    float* PB    = PA    + (size_t)BB * NN * FEAT;   // B*N*64
    float* s1    = PB    + (size_t)BB * NN * FEAT;   // B*N each from here on
    float* s2    = s1    + (size_t)BB * NN;
    float* nt    = s2    + (size_t)BB * NN;
    float* s1s   = nt    + (size_t)BB * NN;
    int*   p1    = (int*)(s1s + (size_t)BB * NN);
    float* s2s   = (float*)p1 + (size_t)BB * NN;
    float* E1suf = s2s   + (size_t)BB * NN;
    float* E2    = E1suf + (size_t)BB * NN;
    float* as    = E2    + (size_t)BB * NN;
    float* bs    = as    + (size_t)BB * NN;
    float* CTA   = bs    + (size_t)BB * NN;          // B*NCH*64
    float* CTB   = CTA   + (size_t)BB * NCH * FEAT;

    k0_ntilde<<<dim3(BB * NN / 256), dim3(256), 0, stream>>>(n, att2, nt);
    k1_conv<<<dim3(NN / BM, BB), dim3(256), 0, stream>>>(x, conv_w, conv_b, xf);
    k2_s2<<<dim3(NN * BB / 256), dim3(256), 0, stream>>>(conv_w, nt, conv_b, att2, s2);
    k2b_s1<<<dim3(BB * NN / 256), dim3(256), 0, stream>>>(xf, att1, s1);
    ksort<<<dim3(2, BB), dim3(1024), 0, stream>>>(s1, s2, s1s, p1, s2s, E1suf, E2);
    k_ab<<<dim3(BB * NN / 256), dim3(256), 0, stream>>>(s1s, s2s, E1suf, E2, as, bs);
    kscanA<<<dim3(NCH, BB), dim3(64), 0, stream>>>(p1, as, bs, xf, CTA, CTB);
    kscanB<<<dim3(NCH, BB), dim3(64), 0, stream>>>(p1, as, bs, xf, CTA, CTB, PA, PB);
    k4_sep<<<dim3(NN / 16, BB), dim3(256), 0, stream>>>(s2, s1s, PA, PB, outp);
}